// Round 3
// baseline (1000.328 us; speedup 1.0000x reference)
//
#include <hip/hip_runtime.h>
#include <cstdint>

#define DDIM 64
#define KCODES 1024
#define OUT_LOSS 8388608   // B*D
#define OUT_IDX  8388610   // B*D + 2 losses

// ---------------------------------------------------------------------------
// Kernel 0: wsq[c] = |W_c|^2   (fast fp32 — screen only)
// ---------------------------------------------------------------------------
__global__ __launch_bounds__(256) void k_wsq(const float* __restrict__ W,
                                             float* __restrict__ wsq) {
    int c = blockIdx.x * 256 + threadIdx.x;
    const float4* wr = (const float4*)(W + (c << 6));
    float a0 = 0.f, a1 = 0.f, a2 = 0.f, a3 = 0.f;
#pragma unroll
    for (int j = 0; j < 16; ++j) {
        float4 w = wr[j];
        a0 = fmaf(w.x, w.x, a0);
        a1 = fmaf(w.y, w.y, a1);
        a2 = fmaf(w.z, w.z, a2);
        a3 = fmaf(w.w, w.w, a3);
    }
    wsq[c] = (a0 + a1) + (a2 + a3);
}

// ---------------------------------------------------------------------------
// Kernel 1: fp32 SCREEN — per-row argmin of v = |w|^2 - 2 z.w, top-2 tracked.
// Rows whose top-2 gap < MARGIN are flagged (negative idx) for ref-emulation.
// MARGIN = 3e-4 is ~10x the fp32-reference's own deviation band (~3.3e-5),
// which itself is ~10x our screen error (~4e-6).
// ---------------------------------------------------------------------------
#define MARGIN 3e-4f

__global__ __launch_bounds__(256, 3) void k_argmin(const float* __restrict__ z_e,
                                                   const float* __restrict__ W,
                                                   const float* __restrict__ wsq,
                                                   float* __restrict__ out_idx) {
    const int wave = threadIdx.x >> 6;
    const int lane = threadIdx.x & 63;
    const int row  = blockIdx.x * 64 + lane;

    float4 zz[16];
    const float4* zp = (const float4*)(z_e + (row << 6));
#pragma unroll
    for (int j = 0; j < 16; ++j) zz[j] = zp[j];

    float best = 1e30f, best2 = 1e30f;
    int   bidx = 0;
    const int k0 = wave << 8;                 // 256 codes per wave
    for (int k = k0; k < k0 + 256; ++k) {
        const float4* wk = (const float4*)(W + (k << 6));
        float a0 = 0.f, a1 = 0.f, a2 = 0.f, a3 = 0.f;
#pragma unroll
        for (int j = 0; j < 16; ++j) {
            float4 w = wk[j];
            a0 = fmaf(zz[j].x, w.x, a0);
            a1 = fmaf(zz[j].y, w.y, a1);
            a2 = fmaf(zz[j].z, w.z, a2);
            a3 = fmaf(zz[j].w, w.w, a3);
        }
        float dot = (a0 + a1) + (a2 + a3);
        float v = fmaf(-2.f, dot, wsq[k]);
        bool lt1 = v < best;                  // strict < keeps first index
        bool lt2 = v < best2;
        best2 = lt1 ? best : (lt2 ? v : best2);
        best  = lt1 ? v : best;
        bidx  = lt1 ? k : bidx;
    }

    __shared__ float s_b1[4][64];
    __shared__ float s_b2[4][64];
    __shared__ int   s_ix[4][64];
    s_b1[wave][lane] = best;
    s_b2[wave][lane] = best2;
    s_ix[wave][lane] = bidx;
    __syncthreads();

    if (threadIdx.x < 64) {
        float g1 = s_b1[0][lane], g2 = s_b2[0][lane];
        int   gi = s_ix[0][lane];
#pragma unroll
        for (int w = 1; w < 4; ++w) {
            float c1 = s_b1[w][lane], c2 = s_b2[w][lane];
            int   ci = s_ix[w][lane];
            if (c1 < g1) { g2 = fminf(g1, c2); g1 = c1; gi = ci; }
            else         { g2 = fminf(g2, c1); }
        }
        bool flag = (g2 - g1) < MARGIN;
        out_idx[blockIdx.x * 64 + lane] = flag ? -(float)(gi + 1) : (float)gi;
    }
}

// ---------------------------------------------------------------------------
// Reference-arithmetic emulation (numpy fp32 on AVX-512 + BLAS sgemm):
//  - sum-of-squares: numpy pairwise for n=64 = elementwise
//      s[j] = (p[j]+p[j+16]) + (p[j+32]+p[j+48]),  then reduce-add tree
//      over 16 lanes with strides 8,4,2,1  (= _mm512_reduce_add_ps).
//  - dot: sgemm microkernel = single accumulator, sequential FMA over k.
//  - D = fl(fl(zsq + wsq_c) - fl(2*dot)); argmin keeps LOWEST index on ties.
// __fmul_rn/__fadd_rn/__fmaf_rn are contraction-proof.
// ---------------------------------------------------------------------------
__device__ __forceinline__ float f4c(const float4& v, int c) {
    return c == 0 ? v.x : c == 1 ? v.y : c == 2 ? v.z : v.w;
}

__device__ __forceinline__ float emu_sumsq(const float4 v[16]) {
    float s[16];
#pragma unroll
    for (int j = 0; j < 16; ++j) {
        float a = f4c(v[(j >> 2)     ], j & 3);
        float b = f4c(v[(j >> 2) + 4 ], j & 3);
        float c = f4c(v[(j >> 2) + 8 ], j & 3);
        float d = f4c(v[(j >> 2) + 12], j & 3);
        float pa = __fmul_rn(a, a), pb = __fmul_rn(b, b);
        float pc = __fmul_rn(c, c), pd = __fmul_rn(d, d);
        s[j] = __fadd_rn(__fadd_rn(pa, pb), __fadd_rn(pc, pd));
    }
    float u[8];
#pragma unroll
    for (int j = 0; j < 8; ++j) u[j] = __fadd_rn(s[j], s[j + 8]);
    float t[4];
#pragma unroll
    for (int j = 0; j < 4; ++j) t[j] = __fadd_rn(u[j], u[j + 4]);
    float w0 = __fadd_rn(t[0], t[2]);
    float w1 = __fadd_rn(t[1], t[3]);
    return __fadd_rn(w0, w1);
}

__device__ void emu_row(int row, const float* __restrict__ z_e,
                        const float* __restrict__ W,
                        float* __restrict__ out_idx, int lane) {
    float4 zz[16];
    const float4* zp = (const float4*)(z_e + (row << 6));
#pragma unroll
    for (int j = 0; j < 16; ++j) zz[j] = zp[j];
    const float zsq = emu_sumsq(zz);

    float bestD = 1e30f;
    int   bestc = KCODES;
    for (int c0 = 0; c0 < KCODES; c0 += 64) {   // lane -> code, ascending
        const int c = c0 + lane;
        const float4* wr = (const float4*)(W + (c << 6));
        float4 ww[16];
#pragma unroll
        for (int j = 0; j < 16; ++j) ww[j] = wr[j];
        const float wsqc = emu_sumsq(ww);
        float acc = 0.f;                        // sequential FMA chain over d
#pragma unroll
        for (int j = 0; j < 16; ++j) {
            acc = __fmaf_rn(zz[j].x, ww[j].x, acc);
            acc = __fmaf_rn(zz[j].y, ww[j].y, acc);
            acc = __fmaf_rn(zz[j].z, ww[j].z, acc);
            acc = __fmaf_rn(zz[j].w, ww[j].w, acc);
        }
        const float twod = __fadd_rn(acc, acc);             // 2*dot (exact)
        const float D = __fadd_rn(__fadd_rn(zsq, wsqc), -twod);
        if (D < bestD) { bestD = D; bestc = c; }            // keeps lowest c
    }
#pragma unroll
    for (int off = 32; off > 0; off >>= 1) {
        float ov = __shfl_down(bestD, off);
        int   oc = __shfl_down(bestc, off);
        if (ov < bestD || (ov == bestD && oc < bestc)) { bestD = ov; bestc = oc; }
    }
    if (lane == 0) out_idx[row] = (float)bestc;
}

__global__ __launch_bounds__(64) void k_rescue(const float* __restrict__ z_e,
                                               const float* __restrict__ W,
                                               float* __restrict__ out_idx) {
    const int lane = threadIdx.x;
    const int base = blockIdx.x * 64;
    float fi = out_idx[base + lane];
    unsigned long long m = __ballot(fi < 0.f);
    while (m) {
        int r = __ffsll(m) - 1;
        m &= m - 1;
        emu_row(base + r, z_e, W, out_idx, lane);
    }
}

// ---------------------------------------------------------------------------
// Kernel 3: gather z_q = W[idx], write z_q_st, per-block partial MSE sums.
// ---------------------------------------------------------------------------
__global__ __launch_bounds__(256) void k_gather(const float* __restrict__ z_e,
                                                const float* __restrict__ W,
                                                const float* __restrict__ out_idx,
                                                float* __restrict__ out_zq,
                                                float* __restrict__ partials) {
    const int tid = blockIdx.x * 256 + threadIdx.x;
    float local = 0.f;
#pragma unroll
    for (int i = 0; i < 8; ++i) {
        int task = tid + i * 262144;          // 1024*256 threads total
        int row = task >> 4, d4 = task & 15;
        int idx = (int)out_idx[row];
        float4 w4 = *(const float4*)(W + (idx << 6) + (d4 << 2));
        float4 z4 = *(const float4*)(z_e + (row << 6) + (d4 << 2));
        *(float4*)(out_zq + (row << 6) + (d4 << 2)) = w4;
        float dx = z4.x - w4.x, dy = z4.y - w4.y;
        float dz = z4.z - w4.z, dw = z4.w - w4.w;
        local += dx * dx + dy * dy + dz * dz + dw * dw;
    }
#pragma unroll
    for (int off = 32; off > 0; off >>= 1) local += __shfl_down(local, off);
    __shared__ float s[4];
    if ((threadIdx.x & 63) == 0) s[threadIdx.x >> 6] = local;
    __syncthreads();
    if (threadIdx.x == 0) partials[blockIdx.x] = (s[0] + s[1]) + (s[2] + s[3]);
}

// ---------------------------------------------------------------------------
// Kernel 4: final loss reduction (both losses identical in forward).
// ---------------------------------------------------------------------------
__global__ __launch_bounds__(256) void k_loss(const float* __restrict__ partials,
                                              float* __restrict__ out) {
    float local = 0.f;
#pragma unroll
    for (int i = 0; i < 4; ++i) local += partials[threadIdx.x + i * 256];
#pragma unroll
    for (int off = 32; off > 0; off >>= 1) local += __shfl_down(local, off);
    __shared__ float s[4];
    if ((threadIdx.x & 63) == 0) s[threadIdx.x >> 6] = local;
    __syncthreads();
    if (threadIdx.x == 0) {
        float loss = ((s[0] + s[1]) + (s[2] + s[3])) * (1.f / 8388608.f);
        out[OUT_LOSS]     = loss;   // commitment_loss
        out[OUT_LOSS + 1] = loss;   // codebook_loss
    }
}

// ---------------------------------------------------------------------------
extern "C" void kernel_launch(void* const* d_in, const int* in_sizes, int n_in,
                              void* d_out, int out_size, void* d_ws, size_t ws_size,
                              hipStream_t stream) {
    const float* z_e = (const float*)d_in[0];
    const float* W   = (const float*)d_in[1];
    float* out       = (float*)d_out;
    float* wsq       = (float*)d_ws;          // 1024 floats
    float* partials  = wsq + KCODES;          // 1024 floats
    float* out_idx   = out + OUT_IDX;         // indices written as float

    k_wsq   <<<4,    256, 0, stream>>>(W, wsq);
    k_argmin<<<2048, 256, 0, stream>>>(z_e, W, wsq, out_idx);
    k_rescue<<<2048, 64,  0, stream>>>(z_e, W, out_idx);
    k_gather<<<1024, 256, 0, stream>>>(z_e, W, out_idx, out, partials);
    k_loss  <<<1,    256, 0, stream>>>(partials, out);
}

// Round 4
// 192.499 us; speedup vs baseline: 5.1965x; 5.1965x over previous
//
#include <hip/hip_runtime.h>
#include <cstdint>

#define DDIM 64
#define KCODES 1024
#define OUT_LOSS 8388608   // B*D
#define OUT_IDX  8388610   // B*D + 2 losses

typedef short bf16x8 __attribute__((ext_vector_type(8)));
typedef float f32x4  __attribute__((ext_vector_type(4)));

__device__ __forceinline__ unsigned short f2bf_rne(float f) {
    unsigned u = __float_as_uint(f);
    u += 0x7fffu + ((u >> 16) & 1u);
    return (unsigned short)(u >> 16);
}

// ---------------------------------------------------------------------------
// k_prep: split W into bf16 hi/lo (RNE).  8192 threads: one (code, 8-group).
// ---------------------------------------------------------------------------
__global__ __launch_bounds__(256) void k_prep(const float* __restrict__ W,
                                              short* __restrict__ w_hi,
                                              short* __restrict__ w_lo) {
    const int gid = blockIdx.x * 256 + threadIdx.x;   // 0..8191
    const int c = gid >> 3, g = gid & 7;
    const float4* wp = (const float4*)(W + c * 64 + g * 8);
    float4 a = wp[0], b = wp[1];
    float f[8] = {a.x, a.y, a.z, a.w, b.x, b.y, b.z, b.w};
    bf16x8 hv, lv;
#pragma unroll
    for (int e = 0; e < 8; ++e) {
        unsigned short hs = f2bf_rne(f[e]);
        float hf = __uint_as_float((unsigned)hs << 16);
        hv[e] = (short)hs;
        lv[e] = (short)f2bf_rne(f[e] - hf);
    }
    *(bf16x8*)(w_hi + c * 64 + g * 8) = hv;
    *(bf16x8*)(w_lo + c * 64 + g * 8) = lv;
}

// ---------------------------------------------------------------------------
// k_wsqh: wsqh[c] = -0.5 * |W_c|^2  (fp32; used as MFMA C-operand init)
// ---------------------------------------------------------------------------
__global__ __launch_bounds__(256) void k_wsqh(const float* __restrict__ W,
                                              float* __restrict__ wsqh) {
    int c = blockIdx.x * 256 + threadIdx.x;
    const float4* wr = (const float4*)(W + (c << 6));
    float a0 = 0.f, a1 = 0.f, a2 = 0.f, a3 = 0.f;
#pragma unroll
    for (int j = 0; j < 16; ++j) {
        float4 w = wr[j];
        a0 = fmaf(w.x, w.x, a0);
        a1 = fmaf(w.y, w.y, a1);
        a2 = fmaf(w.z, w.z, a2);
        a3 = fmaf(w.w, w.w, a3);
    }
    wsqh[c] = -0.5f * ((a0 + a1) + (a2 + a3));
}

// ---------------------------------------------------------------------------
// k_screen: MFMA bf16-split screen.  Block = 1024 thr = 16 waves; wave w owns
// codes [w*64, w*64+64) with W-frags persistent in VGPRs.  Block handles 64
// rows (4 row-tiles of 16).  acc = dot - wsq/2 (wsq folded via C-init);
// argmin of v = wsq - 2dot  <=>  argmax of acc.  Top-2 tracked; rows with
// (b1-b2) < 1.5e-4 (v-gap 3e-4, round-3-proven margin) flagged for rescue.
// ---------------------------------------------------------------------------
__global__ __launch_bounds__(1024, 4) void k_screen(const float* __restrict__ z_e,
                                                    const short* __restrict__ w_hi,
                                                    const short* __restrict__ w_lo,
                                                    const float* __restrict__ wsqh,
                                                    float* __restrict__ out_idx) {
    __shared__ short  s_zh[4096];        // 64 rows x 64 d, 16B-swizzled
    __shared__ short  s_zl[4096];
    __shared__ float4 s_slot[2][256];    // merge slots, double-buffered

    const int tid  = threadIdx.x;
    const int w    = tid >> 6;
    const int lane = tid & 63;
    const int c4   = lane >> 4, r16 = lane & 15;
    const int rowbase = blockIdx.x * 64;

    // --- A-frags: wave's 64 codes, hi+lo, 2 k-steps (64 VGPR) + wsq frags ---
    const int wbase = w * 64;
    bf16x8 wh[4][2], wl[4][2];
    f32x4  wsqf[4];
#pragma unroll
    for (int ct = 0; ct < 4; ++ct) {
        const int code = wbase + ct * 16 + r16;
#pragma unroll
        for (int ks = 0; ks < 2; ++ks) {
            const int off = code * 64 + ks * 32 + c4 * 8;
            wh[ct][ks] = *(const bf16x8*)(w_hi + off);
            wl[ct][ks] = *(const bf16x8*)(w_lo + off);
        }
        wsqf[ct] = *(const f32x4*)(wsqh + wbase + ct * 16 + c4 * 4);
    }

    // --- convert block's 64 z-rows to bf16 hi/lo in LDS (threads 0..511) ---
    if (tid < 512) {
        const int rl = tid >> 3, g = tid & 7;
        const float4* zp = (const float4*)(z_e + (rowbase + rl) * 64 + g * 8);
        float4 a = zp[0], b = zp[1];
        float f[8] = {a.x, a.y, a.z, a.w, b.x, b.y, b.z, b.w};
        bf16x8 hv, lv;
#pragma unroll
        for (int e = 0; e < 8; ++e) {
            unsigned short hs = f2bf_rne(f[e]);
            float hf = __uint_as_float((unsigned)hs << 16);
            hv[e] = (short)hs;
            lv[e] = (short)f2bf_rne(f[e] - hf);
        }
        const int slot = rl * 64 + ((g ^ (rl & 7)) * 8);   // bank-swizzled
        *(bf16x8*)(s_zh + slot) = hv;
        *(bf16x8*)(s_zl + slot) = lv;
    }
    __syncthreads();

    const int lanebase = c4 * 4;
    for (int rt = 0; rt < 4; ++rt) {
        const int buf = rt & 1;
        // B-frags (z rows) from swizzled LDS
        bf16x8 zh[2], zl[2];
#pragma unroll
        for (int ks = 0; ks < 2; ++ks) {
            const int rl = rt * 16 + r16;
            const int g  = ks * 4 + c4;
            const int sl = rl * 64 + ((g ^ (rl & 7)) * 8);
            zh[ks] = *(const bf16x8*)(s_zh + sl);
            zl[ks] = *(const bf16x8*)(s_zl + sl);
        }
        // 24 MFMAs: 3-pass bf16 split, wsq/-2 folded as C-init
        f32x4 acc[4];
#pragma unroll
        for (int ct = 0; ct < 4; ++ct) {
            acc[ct] = __builtin_amdgcn_mfma_f32_16x16x32_bf16(wh[ct][0], zh[0], wsqf[ct], 0, 0, 0);
            acc[ct] = __builtin_amdgcn_mfma_f32_16x16x32_bf16(wh[ct][1], zh[1], acc[ct], 0, 0, 0);
            acc[ct] = __builtin_amdgcn_mfma_f32_16x16x32_bf16(wh[ct][0], zl[0], acc[ct], 0, 0, 0);
            acc[ct] = __builtin_amdgcn_mfma_f32_16x16x32_bf16(wh[ct][1], zl[1], acc[ct], 0, 0, 0);
            acc[ct] = __builtin_amdgcn_mfma_f32_16x16x32_bf16(wl[ct][0], zh[0], acc[ct], 0, 0, 0);
            acc[ct] = __builtin_amdgcn_mfma_f32_16x16x32_bf16(wl[ct][1], zh[1], acc[ct], 0, 0, 0);
        }
        // top-2 MAX tracking over 16 values (D: code=(l>>4)*4+r, row=l&15)
        float b1 = -3.4e38f, b2 = -3.4e38f;
        int rel = 0;
#pragma unroll
        for (int ct = 0; ct < 4; ++ct) {
#pragma unroll
            for (int r = 0; r < 4; ++r) {
                float v = acc[ct][r];
                b2 = fmaxf(b2, fminf(v, b1));   // uses OLD b1
                bool gt = v > b1;
                b1  = gt ? v : b1;
                rel = gt ? (ct * 16 + r) : rel; // inline-const cndmask
            }
        }
        rel += lanebase;
        // merge across the 4 lane-groups (same row, different codes)
#pragma unroll
        for (int m = 16; m <= 32; m <<= 1) {
            float ob1 = __shfl_xor(b1, m);
            float ob2 = __shfl_xor(b2, m);
            int   orl = __shfl_xor(rel, m);
            bool gt = ob1 > b1;
            b2  = gt ? fmaxf(b1, ob2) : fmaxf(b2, ob1);
            b1  = gt ? ob1 : b1;
            rel = gt ? orl : rel;
        }
        // lanes 0..15 publish per-(row, wave-chunk) top-2 to swizzled slots
        if (lane < 16) {
            s_slot[buf][w * 16 + (r16 ^ (w & 7))] =
                make_float4(b1, b2, (float)(wbase + rel), 0.f);
        }
        __syncthreads();
        // wave w merges row rt*16+w across the 16 chunks (all lanes active)
        {
            const int c = r16;   // chunk id (lanes 16+ broadcast-duplicate)
            float4 e = s_slot[buf][c * 16 + (w ^ (c & 7))];
            float mb1 = e.x, mb2 = e.y, mi = e.z;
#pragma unroll
            for (int m = 1; m <= 8; m <<= 1) {
                float ob1 = __shfl_xor(mb1, m);
                float ob2 = __shfl_xor(mb2, m);
                float oi  = __shfl_xor(mi, m);
                bool gt = ob1 > mb1;
                mb2 = gt ? fmaxf(mb1, ob2) : fmaxf(mb2, ob1);
                mb1 = gt ? ob1 : mb1;
                mi  = gt ? oi  : mi;
            }
            if (lane == 0) {
                bool flag = (mb1 - mb2) < 1.5e-4f;   // v-space gap < 3e-4
                out_idx[rowbase + rt * 16 + w] = flag ? -(mi + 1.f) : mi;
            }
        }
    }
}

// ---------------------------------------------------------------------------
// Reference-arithmetic emulation rescue (UNCHANGED from round 3 — proven).
// ---------------------------------------------------------------------------
__device__ __forceinline__ float f4c(const float4& v, int c) {
    return c == 0 ? v.x : c == 1 ? v.y : c == 2 ? v.z : v.w;
}

__device__ __forceinline__ float emu_sumsq(const float4 v[16]) {
    float s[16];
#pragma unroll
    for (int j = 0; j < 16; ++j) {
        float a = f4c(v[(j >> 2)     ], j & 3);
        float b = f4c(v[(j >> 2) + 4 ], j & 3);
        float c = f4c(v[(j >> 2) + 8 ], j & 3);
        float d = f4c(v[(j >> 2) + 12], j & 3);
        float pa = __fmul_rn(a, a), pb = __fmul_rn(b, b);
        float pc = __fmul_rn(c, c), pd = __fmul_rn(d, d);
        s[j] = __fadd_rn(__fadd_rn(pa, pb), __fadd_rn(pc, pd));
    }
    float u[8];
#pragma unroll
    for (int j = 0; j < 8; ++j) u[j] = __fadd_rn(s[j], s[j + 8]);
    float t[4];
#pragma unroll
    for (int j = 0; j < 4; ++j) t[j] = __fadd_rn(u[j], u[j + 4]);
    float w0 = __fadd_rn(t[0], t[2]);
    float w1 = __fadd_rn(t[1], t[3]);
    return __fadd_rn(w0, w1);
}

__device__ void emu_row(int row, const float* __restrict__ z_e,
                        const float* __restrict__ W,
                        float* __restrict__ out_idx, int lane) {
    float4 zz[16];
    const float4* zp = (const float4*)(z_e + (row << 6));
#pragma unroll
    for (int j = 0; j < 16; ++j) zz[j] = zp[j];
    const float zsq = emu_sumsq(zz);

    float bestD = 1e30f;
    int   bestc = KCODES;
    for (int c0 = 0; c0 < KCODES; c0 += 64) {
        const int c = c0 + lane;
        const float4* wr = (const float4*)(W + (c << 6));
        float4 ww[16];
#pragma unroll
        for (int j = 0; j < 16; ++j) ww[j] = wr[j];
        const float wsqc = emu_sumsq(ww);
        float acc = 0.f;
#pragma unroll
        for (int j = 0; j < 16; ++j) {
            acc = __fmaf_rn(zz[j].x, ww[j].x, acc);
            acc = __fmaf_rn(zz[j].y, ww[j].y, acc);
            acc = __fmaf_rn(zz[j].z, ww[j].z, acc);
            acc = __fmaf_rn(zz[j].w, ww[j].w, acc);
        }
        const float twod = __fadd_rn(acc, acc);
        const float D = __fadd_rn(__fadd_rn(zsq, wsqc), -twod);
        if (D < bestD) { bestD = D; bestc = c; }
    }
#pragma unroll
    for (int off = 32; off > 0; off >>= 1) {
        float ov = __shfl_down(bestD, off);
        int   oc = __shfl_down(bestc, off);
        if (ov < bestD || (ov == bestD && oc < bestc)) { bestD = ov; bestc = oc; }
    }
    if (lane == 0) out_idx[row] = (float)bestc;
}

__global__ __launch_bounds__(64) void k_rescue(const float* __restrict__ z_e,
                                               const float* __restrict__ W,
                                               float* __restrict__ out_idx) {
    const int lane = threadIdx.x;
    const int base = blockIdx.x * 64;
    float fi = out_idx[base + lane];
    unsigned long long m = __ballot(fi < 0.f);
    while (m) {
        int r = __ffsll(m) - 1;
        m &= m - 1;
        emu_row(base + r, z_e, W, out_idx, lane);
    }
}

// ---------------------------------------------------------------------------
// k_gather: z_q = W[idx], write z_q_st, per-block partial MSE sums.
// ---------------------------------------------------------------------------
__global__ __launch_bounds__(256) void k_gather(const float* __restrict__ z_e,
                                                const float* __restrict__ W,
                                                const float* __restrict__ out_idx,
                                                float* __restrict__ out_zq,
                                                float* __restrict__ partials) {
    const int tid = blockIdx.x * 256 + threadIdx.x;
    float local = 0.f;
#pragma unroll
    for (int i = 0; i < 8; ++i) {
        int task = tid + i * 262144;
        int row = task >> 4, d4 = task & 15;
        int idx = (int)out_idx[row];
        float4 w4 = *(const float4*)(W + (idx << 6) + (d4 << 2));
        float4 z4 = *(const float4*)(z_e + (row << 6) + (d4 << 2));
        *(float4*)(out_zq + (row << 6) + (d4 << 2)) = w4;
        float dx = z4.x - w4.x, dy = z4.y - w4.y;
        float dz = z4.z - w4.z, dw = z4.w - w4.w;
        local += dx * dx + dy * dy + dz * dz + dw * dw;
    }
#pragma unroll
    for (int off = 32; off > 0; off >>= 1) local += __shfl_down(local, off);
    __shared__ float s[4];
    if ((threadIdx.x & 63) == 0) s[threadIdx.x >> 6] = local;
    __syncthreads();
    if (threadIdx.x == 0) partials[blockIdx.x] = (s[0] + s[1]) + (s[2] + s[3]);
}

// ---------------------------------------------------------------------------
// k_loss: final reduction (both losses identical in forward).
// ---------------------------------------------------------------------------
__global__ __launch_bounds__(256) void k_loss(const float* __restrict__ partials,
                                              float* __restrict__ out) {
    float local = 0.f;
#pragma unroll
    for (int i = 0; i < 4; ++i) local += partials[threadIdx.x + i * 256];
#pragma unroll
    for (int off = 32; off > 0; off >>= 1) local += __shfl_down(local, off);
    __shared__ float s[4];
    if ((threadIdx.x & 63) == 0) s[threadIdx.x >> 6] = local;
    __syncthreads();
    if (threadIdx.x == 0) {
        float loss = ((s[0] + s[1]) + (s[2] + s[3])) * (1.f / 8388608.f);
        out[OUT_LOSS]     = loss;
        out[OUT_LOSS + 1] = loss;
    }
}

// ---------------------------------------------------------------------------
extern "C" void kernel_launch(void* const* d_in, const int* in_sizes, int n_in,
                              void* d_out, int out_size, void* d_ws, size_t ws_size,
                              hipStream_t stream) {
    const float* z_e = (const float*)d_in[0];
    const float* W   = (const float*)d_in[1];
    float* out       = (float*)d_out;

    short* w_hi     = (short*)d_ws;                 // 128 KB
    short* w_lo     = w_hi + KCODES * DDIM;         // 128 KB
    float* wsqh     = (float*)(w_lo + KCODES * DDIM);  // 4 KB
    float* partials = wsqh + KCODES;                // 4 KB
    float* out_idx  = out + OUT_IDX;

    k_prep  <<<32,   256,  0, stream>>>(W, w_hi, w_lo);
    k_wsqh  <<<4,    256,  0, stream>>>(W, wsqh);
    k_screen<<<2048, 1024, 0, stream>>>(z_e, w_hi, w_lo, wsqh, out_idx);
    k_rescue<<<2048, 64,   0, stream>>>(z_e, W, out_idx);
    k_gather<<<1024, 256,  0, stream>>>(z_e, W, out_idx, out, partials);
    k_loss  <<<1,    256,  0, stream>>>(partials, out);
}

// Round 5
// 166.409 us; speedup vs baseline: 6.0112x; 1.1568x over previous
//
#include <hip/hip_runtime.h>
#include <cstdint>

#define KCODES 1024
#define OUT_LOSS 8388608   // B*D
#define OUT_IDX  8388610   // B*D + 2 losses

typedef short bf16x8 __attribute__((ext_vector_type(8)));
typedef float f32x4  __attribute__((ext_vector_type(4)));
typedef unsigned u32x4 __attribute__((ext_vector_type(4)));

union frag { u32x4 u; bf16x8 h; };

__device__ __forceinline__ unsigned short f2bf_rne(float f) {
    unsigned u = __float_as_uint(f);
    u += 0x7fffu + ((u >> 16) & 1u);
    return (unsigned short)(u >> 16);
}
__device__ __forceinline__ void split_pair(float a, float b, unsigned& hi, unsigned& lo) {
    unsigned ha = f2bf_rne(a), hb = f2bf_rne(b);
    hi = ha | (hb << 16);
    float ra = a - __uint_as_float(ha << 16);
    float rb = b - __uint_as_float(hb << 16);
    lo = (unsigned)f2bf_rne(ra) | ((unsigned)f2bf_rne(rb) << 16);
}

// ---------------------------------------------------------------------------
// k_prep: fused W bf16 hi/lo split + wsqh[c] = -0.5*|W_c|^2 (C-operand init).
// 1024 threads, one code each (tiny, L2-resident).
// ---------------------------------------------------------------------------
__global__ __launch_bounds__(256) void k_prep(const float* __restrict__ W,
                                              short* __restrict__ w_hi,
                                              short* __restrict__ w_lo,
                                              float* __restrict__ wsqh) {
    const int c = blockIdx.x * 256 + threadIdx.x;
    const float4* wr = (const float4*)(W + (c << 6));
    float a0 = 0.f, a1 = 0.f, a2 = 0.f, a3 = 0.f;
#pragma unroll
    for (int j = 0; j < 8; ++j) {
        float4 p = wr[2 * j], q = wr[2 * j + 1];
        a0 = fmaf(p.x, p.x, a0); a1 = fmaf(p.y, p.y, a1);
        a2 = fmaf(p.z, p.z, a2); a3 = fmaf(p.w, p.w, a3);
        a0 = fmaf(q.x, q.x, a0); a1 = fmaf(q.y, q.y, a1);
        a2 = fmaf(q.z, q.z, a2); a3 = fmaf(q.w, q.w, a3);
        unsigned h0, h1, h2, h3, l0, l1, l2, l3;
        split_pair(p.x, p.y, h0, l0); split_pair(p.z, p.w, h1, l1);
        split_pair(q.x, q.y, h2, l2); split_pair(q.z, q.w, h3, l3);
        u32x4 hv = {h0, h1, h2, h3}, lv = {l0, l1, l2, l3};
        *(u32x4*)(w_hi + (c << 6) + j * 8) = hv;
        *(u32x4*)(w_lo + (c << 6) + j * 8) = lv;
    }
    wsqh[c] = -0.5f * ((a0 + a1) + (a2 + a3));
}

// ---------------------------------------------------------------------------
// k_screen: barrier-free MFMA screen.  One wave = 64 rows (z hi/lo frags
// persistent in VGPRs), streams all 64 W code-tiles from L2.  3-pass bf16
// split, wsq folded as C-init: acc = dot - wsq/2; argmin v <=> argmax acc.
// Packed-int top-2: u = (acc_bits & ~1023) | code_idx, signed-int max.
// (Best acc is always positive -> int order == float order where it matters;
// negatives order below all positives; mis-order among negatives only occurs
// when the gap is huge -> correctly unflagged.)
// ---------------------------------------------------------------------------
__global__ __launch_bounds__(256, 2) void k_screen(const float* __restrict__ z_e,
                                                   const short* __restrict__ w_hi,
                                                   const short* __restrict__ w_lo,
                                                   const float* __restrict__ wsqh,
                                                   float* __restrict__ out_idx) {
    const int lane = threadIdx.x & 63;
    const int wid  = (blockIdx.x << 2) + (threadIdx.x >> 6);   // 0..2047
    const int c4 = lane >> 4, r16 = lane & 15;
    const int rowbase = wid << 6;

    // persistent z fragments: subtile s (rows s*16..+16), k-step ks
    frag zh[4][2], zl[4][2];
#pragma unroll
    for (int s = 0; s < 4; ++s) {
        const float* zr = z_e + (size_t)(rowbase + s * 16 + r16) * 64;
#pragma unroll
        for (int ks = 0; ks < 2; ++ks) {
            float4 p = *(const float4*)(zr + ks * 32 + c4 * 8);
            float4 q = *(const float4*)(zr + ks * 32 + c4 * 8 + 4);
            unsigned h0, h1, h2, h3, l0, l1, l2, l3;
            split_pair(p.x, p.y, h0, l0); split_pair(p.z, p.w, h1, l1);
            split_pair(q.x, q.y, h2, l2); split_pair(q.z, q.w, h3, l3);
            zh[s][ks].u = (u32x4){h0, h1, h2, h3};
            zl[s][ks].u = (u32x4){l0, l1, l2, l3};
        }
    }

    int b1[4], b2[4];
#pragma unroll
    for (int s = 0; s < 4; ++s) { b1[s] = (int)0x80000000; b2[s] = (int)0x80000000; }

    const int vlaneor = c4 << 2;

#pragma unroll 2
    for (int t = 0; t < 64; ++t) {
        const int cbase = t << 4;
        const int woff  = (cbase + r16) * 64 + c4 * 8;
        frag whf[2], wlf[2];
        whf[0].u = *(const u32x4*)(w_hi + woff);
        whf[1].u = *(const u32x4*)(w_hi + woff + 32);
        wlf[0].u = *(const u32x4*)(w_lo + woff);
        wlf[1].u = *(const u32x4*)(w_lo + woff + 32);
        const f32x4 wsqf = *(const f32x4*)(wsqh + cbase + c4 * 4);
        const int orbase = cbase | vlaneor;

#pragma unroll
        for (int s = 0; s < 4; ++s) {
            f32x4 acc;
            acc = __builtin_amdgcn_mfma_f32_16x16x32_bf16(whf[0].h, zh[s][0].h, wsqf, 0, 0, 0);
            acc = __builtin_amdgcn_mfma_f32_16x16x32_bf16(whf[1].h, zh[s][1].h, acc, 0, 0, 0);
            acc = __builtin_amdgcn_mfma_f32_16x16x32_bf16(whf[0].h, zl[s][0].h, acc, 0, 0, 0);
            acc = __builtin_amdgcn_mfma_f32_16x16x32_bf16(whf[1].h, zl[s][1].h, acc, 0, 0, 0);
            acc = __builtin_amdgcn_mfma_f32_16x16x32_bf16(wlf[0].h, zh[s][0].h, acc, 0, 0, 0);
            acc = __builtin_amdgcn_mfma_f32_16x16x32_bf16(wlf[1].h, zh[s][1].h, acc, 0, 0, 0);
#pragma unroll
            for (int r = 0; r < 4; ++r) {
                int u = (__float_as_int(acc[r]) & (int)0xFFFFFC00) | (orbase + r);
                b2[s] = max(b2[s], min(u, b1[s]));
                b1[s] = max(b1[s], u);
            }
        }
    }

    // merge across the 4 lane-groups (xor 16, 32), then write
#pragma unroll
    for (int s = 0; s < 4; ++s) {
        int x1 = b1[s], x2 = b2[s];
#pragma unroll
        for (int m = 16; m <= 32; m <<= 1) {
            int o1 = __shfl_xor(x1, m);
            int o2 = __shfl_xor(x2, m);
            x2 = max(max(x2, o2), min(x1, o1));
            x1 = max(x1, o1);
        }
        if (lane < 16) {
            float t1 = __int_as_float(x1 & (int)0xFFFFFC00);
            float t2 = __int_as_float(x2 & (int)0xFFFFFC00);
            int idx = x1 & 1023;
            float M = fmaf(fabsf(t1), 2.6e-4f, 1.6e-4f);   // base + quantization
            bool flag = (t1 - t2) < M;
            out_idx[rowbase + s * 16 + r16] = flag ? -(float)(idx + 1) : (float)idx;
        }
    }
}

// ---------------------------------------------------------------------------
// Reference-arithmetic emulation rescue (UNCHANGED from round 3 — proven).
// ---------------------------------------------------------------------------
__device__ __forceinline__ float f4c(const float4& v, int c) {
    return c == 0 ? v.x : c == 1 ? v.y : c == 2 ? v.z : v.w;
}

__device__ __forceinline__ float emu_sumsq(const float4 v[16]) {
    float s[16];
#pragma unroll
    for (int j = 0; j < 16; ++j) {
        float a = f4c(v[(j >> 2)     ], j & 3);
        float b = f4c(v[(j >> 2) + 4 ], j & 3);
        float c = f4c(v[(j >> 2) + 8 ], j & 3);
        float d = f4c(v[(j >> 2) + 12], j & 3);
        float pa = __fmul_rn(a, a), pb = __fmul_rn(b, b);
        float pc = __fmul_rn(c, c), pd = __fmul_rn(d, d);
        s[j] = __fadd_rn(__fadd_rn(pa, pb), __fadd_rn(pc, pd));
    }
    float u[8];
#pragma unroll
    for (int j = 0; j < 8; ++j) u[j] = __fadd_rn(s[j], s[j + 8]);
    float t[4];
#pragma unroll
    for (int j = 0; j < 4; ++j) t[j] = __fadd_rn(u[j], u[j + 4]);
    float w0 = __fadd_rn(t[0], t[2]);
    float w1 = __fadd_rn(t[1], t[3]);
    return __fadd_rn(w0, w1);
}

__device__ void emu_row(int row, const float* __restrict__ z_e,
                        const float* __restrict__ W,
                        float* __restrict__ out_idx, int lane) {
    float4 zz[16];
    const float4* zp = (const float4*)(z_e + ((size_t)row << 6));
#pragma unroll
    for (int j = 0; j < 16; ++j) zz[j] = zp[j];
    const float zsq = emu_sumsq(zz);

    float bestD = 1e30f;
    int   bestc = KCODES;
    for (int c0 = 0; c0 < KCODES; c0 += 64) {
        const int c = c0 + lane;
        const float4* wr = (const float4*)(W + (c << 6));
        float4 ww[16];
#pragma unroll
        for (int j = 0; j < 16; ++j) ww[j] = wr[j];
        const float wsqc = emu_sumsq(ww);
        float acc = 0.f;
#pragma unroll
        for (int j = 0; j < 16; ++j) {
            acc = __fmaf_rn(zz[j].x, ww[j].x, acc);
            acc = __fmaf_rn(zz[j].y, ww[j].y, acc);
            acc = __fmaf_rn(zz[j].z, ww[j].z, acc);
            acc = __fmaf_rn(zz[j].w, ww[j].w, acc);
        }
        const float twod = __fadd_rn(acc, acc);
        const float D = __fadd_rn(__fadd_rn(zsq, wsqc), -twod);
        if (D < bestD) { bestD = D; bestc = c; }
    }
#pragma unroll
    for (int off = 32; off > 0; off >>= 1) {
        float ov = __shfl_down(bestD, off);
        int   oc = __shfl_down(bestc, off);
        if (ov < bestD || (ov == bestD && oc < bestc)) { bestD = ov; bestc = oc; }
    }
    if (lane == 0) out_idx[row] = (float)bestc;
}

__global__ __launch_bounds__(64) void k_rescue(const float* __restrict__ z_e,
                                               const float* __restrict__ W,
                                               float* __restrict__ out_idx) {
    const int lane = threadIdx.x;
    const int base = blockIdx.x * 64;
    float fi = out_idx[base + lane];
    unsigned long long m = __ballot(fi < 0.f);
    while (m) {
        int r = __ffsll(m) - 1;
        m &= m - 1;
        emu_row(base + r, z_e, W, out_idx, lane);
    }
}

// ---------------------------------------------------------------------------
// k_gather: z_q = W[idx], write z_q_st, per-block partial MSE sums.
// ---------------------------------------------------------------------------
__global__ __launch_bounds__(256) void k_gather(const float* __restrict__ z_e,
                                                const float* __restrict__ W,
                                                const float* __restrict__ out_idx,
                                                float* __restrict__ out_zq,
                                                float* __restrict__ partials) {
    const int tid = blockIdx.x * 256 + threadIdx.x;
    float local = 0.f;
#pragma unroll
    for (int i = 0; i < 8; ++i) {
        int task = tid + i * 262144;
        int row = task >> 4, d4 = task & 15;
        int idx = (int)out_idx[row];
        float4 w4 = *(const float4*)(W + (idx << 6) + (d4 << 2));
        float4 z4 = *(const float4*)(z_e + ((size_t)row << 6) + (d4 << 2));
        *(float4*)(out_zq + ((size_t)row << 6) + (d4 << 2)) = w4;
        float dx = z4.x - w4.x, dy = z4.y - w4.y;
        float dz = z4.z - w4.z, dw = z4.w - w4.w;
        local += dx * dx + dy * dy + dz * dz + dw * dw;
    }
#pragma unroll
    for (int off = 32; off > 0; off >>= 1) local += __shfl_down(local, off);
    __shared__ float s[4];
    if ((threadIdx.x & 63) == 0) s[threadIdx.x >> 6] = local;
    __syncthreads();
    if (threadIdx.x == 0) partials[blockIdx.x] = (s[0] + s[1]) + (s[2] + s[3]);
}

// ---------------------------------------------------------------------------
// k_loss: final reduction (both losses identical in forward).
// ---------------------------------------------------------------------------
__global__ __launch_bounds__(256) void k_loss(const float* __restrict__ partials,
                                              float* __restrict__ out) {
    float local = 0.f;
#pragma unroll
    for (int i = 0; i < 4; ++i) local += partials[threadIdx.x + i * 256];
#pragma unroll
    for (int off = 32; off > 0; off >>= 1) local += __shfl_down(local, off);
    __shared__ float s[4];
    if ((threadIdx.x & 63) == 0) s[threadIdx.x >> 6] = local;
    __syncthreads();
    if (threadIdx.x == 0) {
        float loss = ((s[0] + s[1]) + (s[2] + s[3])) * (1.f / 8388608.f);
        out[OUT_LOSS]     = loss;
        out[OUT_LOSS + 1] = loss;
    }
}

// ---------------------------------------------------------------------------
extern "C" void kernel_launch(void* const* d_in, const int* in_sizes, int n_in,
                              void* d_out, int out_size, void* d_ws, size_t ws_size,
                              hipStream_t stream) {
    const float* z_e = (const float*)d_in[0];
    const float* W   = (const float*)d_in[1];
    float* out       = (float*)d_out;

    short* w_hi     = (short*)d_ws;                     // 128 KB
    short* w_lo     = w_hi + KCODES * 64;               // 128 KB
    float* wsqh     = (float*)(w_lo + KCODES * 64);     // 4 KB
    float* partials = wsqh + KCODES;                    // 4 KB
    float* out_idx  = out + OUT_IDX;

    k_prep  <<<4,    256, 0, stream>>>(W, w_hi, w_lo, wsqh);
    k_screen<<<512,  256, 0, stream>>>(z_e, w_hi, w_lo, wsqh, out_idx);
    k_rescue<<<2048, 64,  0, stream>>>(z_e, W, out_idx);
    k_gather<<<1024, 256, 0, stream>>>(z_e, W, out_idx, out, partials);
    k_loss  <<<1,    256, 0, stream>>>(partials, out);
}

// Round 6
// 163.176 us; speedup vs baseline: 6.1304x; 1.0198x over previous
//
#include <hip/hip_runtime.h>
#include <cstdint>

#define KCODES 1024
#define OUT_LOSS 8388608   // B*D
#define OUT_IDX  8388610   // B*D + 2 losses

typedef short bf16x8 __attribute__((ext_vector_type(8)));
typedef float f32x4  __attribute__((ext_vector_type(4)));
typedef unsigned u32x4 __attribute__((ext_vector_type(4)));

union frag { u32x4 u; bf16x8 h; };

__device__ __forceinline__ unsigned short f2bf_rne(float f) {
    unsigned u = __float_as_uint(f);
    u += 0x7fffu + ((u >> 16) & 1u);
    return (unsigned short)(u >> 16);
}
__device__ __forceinline__ void split_pair(float a, float b, unsigned& hi, unsigned& lo) {
    unsigned ha = f2bf_rne(a), hb = f2bf_rne(b);
    hi = ha | (hb << 16);
    float ra = a - __uint_as_float(ha << 16);
    float rb = b - __uint_as_float(hb << 16);
    lo = (unsigned)f2bf_rne(ra) | ((unsigned)f2bf_rne(rb) << 16);
}

// ---------------------------------------------------------------------------
// k_prep: W bf16 hi/lo split + wsqh[c] = -0.5*|W_c|^2 (MFMA C-operand init).
// ---------------------------------------------------------------------------
__global__ __launch_bounds__(256) void k_prep(const float* __restrict__ W,
                                              short* __restrict__ w_hi,
                                              short* __restrict__ w_lo,
                                              float* __restrict__ wsqh) {
    const int c = blockIdx.x * 256 + threadIdx.x;
    const float4* wr = (const float4*)(W + (c << 6));
    float a0 = 0.f, a1 = 0.f, a2 = 0.f, a3 = 0.f;
#pragma unroll
    for (int j = 0; j < 8; ++j) {
        float4 p = wr[2 * j], q = wr[2 * j + 1];
        a0 = fmaf(p.x, p.x, a0); a1 = fmaf(p.y, p.y, a1);
        a2 = fmaf(p.z, p.z, a2); a3 = fmaf(p.w, p.w, a3);
        a0 = fmaf(q.x, q.x, a0); a1 = fmaf(q.y, q.y, a1);
        a2 = fmaf(q.z, q.z, a2); a3 = fmaf(q.w, q.w, a3);
        unsigned h0, h1, h2, h3, l0, l1, l2, l3;
        split_pair(p.x, p.y, h0, l0); split_pair(p.z, p.w, h1, l1);
        split_pair(q.x, q.y, h2, l2); split_pair(q.z, q.w, h3, l3);
        u32x4 hv = {h0, h1, h2, h3}, lv = {l0, l1, l2, l3};
        *(u32x4*)(w_hi + (c << 6) + j * 8) = hv;
        *(u32x4*)(w_lo + (c << 6) + j * 8) = lv;
    }
    wsqh[c] = -0.5f * ((a0 + a1) + (a2 + a3));
}

// ---------------------------------------------------------------------------
// Reference-arithmetic emulation (proven in rounds 3-5): numpy fp32 pairwise
// sumsq + sgemm sequential-FMA dot; returns exact ref D and argmin (lowest
// index on fp32 ties).  Whole wave per row; result via LDS slots.
// ---------------------------------------------------------------------------
__device__ __forceinline__ float f4c(const float4& v, int c) {
    return c == 0 ? v.x : c == 1 ? v.y : c == 2 ? v.z : v.w;
}

__device__ __forceinline__ float emu_sumsq(const float4 v[16]) {
    float s[16];
#pragma unroll
    for (int j = 0; j < 16; ++j) {
        float a = f4c(v[(j >> 2)     ], j & 3);
        float b = f4c(v[(j >> 2) + 4 ], j & 3);
        float c = f4c(v[(j >> 2) + 8 ], j & 3);
        float d = f4c(v[(j >> 2) + 12], j & 3);
        float pa = __fmul_rn(a, a), pb = __fmul_rn(b, b);
        float pc = __fmul_rn(c, c), pd = __fmul_rn(d, d);
        s[j] = __fadd_rn(__fadd_rn(pa, pb), __fadd_rn(pc, pd));
    }
    float u[8];
#pragma unroll
    for (int j = 0; j < 8; ++j) u[j] = __fadd_rn(s[j], s[j + 8]);
    float t[4];
#pragma unroll
    for (int j = 0; j < 4; ++j) t[j] = __fadd_rn(u[j], u[j + 4]);
    float w0 = __fadd_rn(t[0], t[2]);
    float w1 = __fadd_rn(t[1], t[3]);
    return __fadd_rn(w0, w1);
}

__device__ void emu_row(int row, const float* __restrict__ z_e,
                        const float* __restrict__ W, int lane,
                        int* __restrict__ out_i, float* __restrict__ out_l) {
    float4 zz[16];
    const float4* zp = (const float4*)(z_e + ((size_t)row << 6));
#pragma unroll
    for (int j = 0; j < 16; ++j) zz[j] = zp[j];
    const float zsq = emu_sumsq(zz);

    float bestD = 1e30f;
    int   bestc = KCODES;
    for (int c0 = 0; c0 < KCODES; c0 += 64) {
        const int c = c0 + lane;
        const float4* wr = (const float4*)(W + (c << 6));
        float4 ww[16];
#pragma unroll
        for (int j = 0; j < 16; ++j) ww[j] = wr[j];
        const float wsqc = emu_sumsq(ww);
        float acc = 0.f;
#pragma unroll
        for (int j = 0; j < 16; ++j) {
            acc = __fmaf_rn(zz[j].x, ww[j].x, acc);
            acc = __fmaf_rn(zz[j].y, ww[j].y, acc);
            acc = __fmaf_rn(zz[j].z, ww[j].z, acc);
            acc = __fmaf_rn(zz[j].w, ww[j].w, acc);
        }
        const float twod = __fadd_rn(acc, acc);
        const float D = __fadd_rn(__fadd_rn(zsq, wsqc), -twod);
        if (D < bestD) { bestD = D; bestc = c; }
    }
#pragma unroll
    for (int off = 32; off > 0; off >>= 1) {
        float ov = __shfl_down(bestD, off);
        int   oc = __shfl_down(bestc, off);
        if (ov < bestD || (ov == bestD && oc < bestc)) { bestD = ov; bestc = oc; }
    }
    if (lane == 0) { *out_i = bestc; *out_l = bestD; }
}

// ---------------------------------------------------------------------------
// k_mega: fused screen + rescue + gather + loss-partial.
// Block = 128 thr = 2 waves sharing 64 rows; wave w scans codes [512w,512w+512)
// (K-split -> 4096 waves = 4/SIMD).  z hi/lo frags persistent in VGPRs; W
// code-tiles streamed from L2.  acc = dot - wsq/2 (C-init); argmin v <=>
// argmax acc; packed-int top-2 (idx in low 10 bits).  End: LDS cross-wave
// top-2 merge, flag near-ties, in-block ref-emulation rescue, then write
// z_q_st = W[idx] (exact), indices, and loss_row = zsq - 2*t1 partials.
// ---------------------------------------------------------------------------
__global__ __launch_bounds__(128, 4) void k_mega(const float* __restrict__ z_e,
                                                 const short* __restrict__ w_hi,
                                                 const short* __restrict__ w_lo,
                                                 const float* __restrict__ wsqh,
                                                 const float* __restrict__ W,
                                                 float* __restrict__ out_zq,
                                                 float* __restrict__ out_idx_f,
                                                 float* __restrict__ partials) {
    const int w    = threadIdx.x >> 6;
    const int lane = threadIdx.x & 63;
    const int c4 = lane >> 4, r16 = lane & 15;
    const int rowbase = blockIdx.x << 6;

    // --- persistent z fragments + per-row |z|^2 ---
    frag zh[4][2], zl[4][2];
    float zsq[4];
#pragma unroll
    for (int s = 0; s < 4; ++s) {
        const float* zr = z_e + (size_t)(rowbase + s * 16 + r16) * 64;
        float a = 0.f;
#pragma unroll
        for (int ks = 0; ks < 2; ++ks) {
            float4 p = *(const float4*)(zr + ks * 32 + c4 * 8);
            float4 q = *(const float4*)(zr + ks * 32 + c4 * 8 + 4);
            unsigned h0, h1, h2, h3, l0, l1, l2, l3;
            split_pair(p.x, p.y, h0, l0); split_pair(p.z, p.w, h1, l1);
            split_pair(q.x, q.y, h2, l2); split_pair(q.z, q.w, h3, l3);
            zh[s][ks].u = (u32x4){h0, h1, h2, h3};
            zl[s][ks].u = (u32x4){l0, l1, l2, l3};
            a = fmaf(p.x, p.x, a); a = fmaf(p.y, p.y, a);
            a = fmaf(p.z, p.z, a); a = fmaf(p.w, p.w, a);
            a = fmaf(q.x, q.x, a); a = fmaf(q.y, q.y, a);
            a = fmaf(q.z, q.z, a); a = fmaf(q.w, q.w, a);
        }
        a += __shfl_xor(a, 16);
        a += __shfl_xor(a, 32);
        zsq[s] = a;            // valid on all lanes; row = s*16 + r16
    }

    // --- K-split screen: wave w covers 32 code-tiles of 16 ---
    int b1[4], b2[4];
#pragma unroll
    for (int s = 0; s < 4; ++s) { b1[s] = (int)0x80000000; b2[s] = (int)0x80000000; }
    const int vlaneor = c4 << 2;

#pragma unroll 2
    for (int tt = 0; tt < 32; ++tt) {
        const int cbase = ((w << 5) + tt) << 4;
        const int woff  = (cbase + r16) * 64 + c4 * 8;
        frag whf[2], wlf[2];
        whf[0].u = *(const u32x4*)(w_hi + woff);
        whf[1].u = *(const u32x4*)(w_hi + woff + 32);
        wlf[0].u = *(const u32x4*)(w_lo + woff);
        wlf[1].u = *(const u32x4*)(w_lo + woff + 32);
        const f32x4 wsqf = *(const f32x4*)(wsqh + cbase + c4 * 4);
        const int orbase = cbase | vlaneor;

#pragma unroll
        for (int s = 0; s < 4; ++s) {
            f32x4 acc;
            acc = __builtin_amdgcn_mfma_f32_16x16x32_bf16(whf[0].h, zh[s][0].h, wsqf, 0, 0, 0);
            acc = __builtin_amdgcn_mfma_f32_16x16x32_bf16(whf[1].h, zh[s][1].h, acc, 0, 0, 0);
            acc = __builtin_amdgcn_mfma_f32_16x16x32_bf16(whf[0].h, zl[s][0].h, acc, 0, 0, 0);
            acc = __builtin_amdgcn_mfma_f32_16x16x32_bf16(whf[1].h, zl[s][1].h, acc, 0, 0, 0);
            acc = __builtin_amdgcn_mfma_f32_16x16x32_bf16(wlf[0].h, zh[s][0].h, acc, 0, 0, 0);
            acc = __builtin_amdgcn_mfma_f32_16x16x32_bf16(wlf[1].h, zh[s][1].h, acc, 0, 0, 0);
#pragma unroll
            for (int r = 0; r < 4; ++r) {
                int u = (__float_as_int(acc[r]) & (int)0xFFFFFC00) | (orbase + r);
                b2[s] = max(b2[s], min(u, b1[s]));
                b1[s] = max(b1[s], u);
            }
        }
    }

    // --- in-wave merge across the 4 lane-groups ---
    int x1a[4], x2a[4];
#pragma unroll
    for (int s = 0; s < 4; ++s) {
        int x1 = b1[s], x2 = b2[s];
#pragma unroll
        for (int m = 16; m <= 32; m <<= 1) {
            int o1 = __shfl_xor(x1, m);
            int o2 = __shfl_xor(x2, m);
            x2 = max(max(x2, o2), min(x1, o1));
            x1 = max(x1, o1);
        }
        x1a[s] = x1; x2a[s] = x2;
    }

    // --- cross-wave merge via LDS ---
    __shared__ uint2 s_w1[64];
    __shared__ int   s_idx[64];
    __shared__ float s_loss[64];
    __shared__ unsigned long long s_flags;

    if (w == 1 && lane < 16) {
#pragma unroll
        for (int s = 0; s < 4; ++s)
            s_w1[s * 16 + r16] = make_uint2((unsigned)x1a[s], (unsigned)x2a[s]);
    }
    __syncthreads();

    if (w == 0) {
        unsigned long long flags64 = 0;
#pragma unroll
        for (int s = 0; s < 4; ++s) {
            bool flag = false;
            if (lane < 16) {
                uint2 o = s_w1[s * 16 + r16];
                int o1 = (int)o.x, o2 = (int)o.y;
                int x1 = x1a[s], x2 = x2a[s];
                x2 = max(max(x2, o2), min(x1, o1));
                x1 = max(x1, o1);
                float t1 = __int_as_float(x1 & (int)0xFFFFFC00);
                float t2 = __int_as_float(x2 & (int)0xFFFFFC00);
                float M = fmaf(fabsf(t1), 2.6e-4f, 1.6e-4f);
                flag = (t1 - t2) < M;
                s_idx[s * 16 + r16]  = x1 & 1023;
                s_loss[s * 16 + r16] = fmaf(-2.f, t1, zsq[s]);
            }
            flags64 |= (__ballot(flag) & 0xFFFFull) << (16 * s);
        }
        if (lane == 0) s_flags = flags64;
    }
    __syncthreads();

    // --- in-block rescue of flagged rows (wave w takes rows [32w, 32w+32)) ---
    {
        const unsigned long long fl = s_flags;
        unsigned m = (w == 0) ? (unsigned)(fl & 0xFFFFFFFFull)
                              : (unsigned)(fl >> 32);
        const int half = w << 5;
        while (m) {
            int r = __ffs(m) - 1;
            m &= m - 1;
            emu_row(rowbase + half + r, z_e, W, lane,
                    &s_idx[half + r], &s_loss[half + r]);
        }
    }
    __syncthreads();

    // --- outputs ---
    if (w == 0) {
        out_idx_f[rowbase + lane] = (float)s_idx[lane];
    } else {
        float v = s_loss[lane];
#pragma unroll
        for (int off = 32; off > 0; off >>= 1) v += __shfl_down(v, off);
        if (lane == 0) partials[blockIdx.x] = v;
    }
    const int half = w << 5;
#pragma unroll
    for (int rp = 0; rp < 8; ++rp) {
        const int rl  = half + rp * 4 + (lane >> 4);
        const int d4  = (lane & 15) << 2;
        const int idx = s_idx[rl];
        float4 w4 = *(const float4*)(W + (idx << 6) + d4);
        *(float4*)(out_zq + (size_t)(rowbase + rl) * 64 + d4) = w4;
    }
}

// ---------------------------------------------------------------------------
// k_loss: reduce 2048 block partials (both losses identical in forward).
// ---------------------------------------------------------------------------
__global__ __launch_bounds__(256) void k_loss(const float* __restrict__ partials,
                                              float* __restrict__ out) {
    float local = 0.f;
#pragma unroll
    for (int i = 0; i < 8; ++i) local += partials[threadIdx.x + i * 256];
#pragma unroll
    for (int off = 32; off > 0; off >>= 1) local += __shfl_down(local, off);
    __shared__ float s[4];
    if ((threadIdx.x & 63) == 0) s[threadIdx.x >> 6] = local;
    __syncthreads();
    if (threadIdx.x == 0) {
        float loss = ((s[0] + s[1]) + (s[2] + s[3])) * (1.f / 8388608.f);
        out[OUT_LOSS]     = loss;
        out[OUT_LOSS + 1] = loss;
    }
}

// ---------------------------------------------------------------------------
extern "C" void kernel_launch(void* const* d_in, const int* in_sizes, int n_in,
                              void* d_out, int out_size, void* d_ws, size_t ws_size,
                              hipStream_t stream) {
    const float* z_e = (const float*)d_in[0];
    const float* W   = (const float*)d_in[1];
    float* out       = (float*)d_out;

    short* w_hi     = (short*)d_ws;                     // 128 KB
    short* w_lo     = w_hi + KCODES * 64;               // 128 KB
    float* wsqh     = (float*)(w_lo + KCODES * 64);     // 4 KB
    float* partials = wsqh + KCODES;                    // 8 KB
    float* out_idx  = out + OUT_IDX;

    k_prep<<<4,    256, 0, stream>>>(W, w_hi, w_lo, wsqh);
    k_mega<<<2048, 128, 0, stream>>>(z_e, w_hi, w_lo, wsqh, W, out, out_idx, partials);
    k_loss<<<1,    256, 0, stream>>>(partials, out);
}

// Round 7
// 148.051 us; speedup vs baseline: 6.7566x; 1.1022x over previous
//
#include <hip/hip_runtime.h>
#include <cstdint>

#define KCODES 1024
#define OUT_LOSS 8388608   // B*D
#define OUT_IDX  8388610   // B*D + 2 losses

typedef short bf16x8 __attribute__((ext_vector_type(8)));
typedef float f32x4  __attribute__((ext_vector_type(4)));
typedef unsigned u32x4 __attribute__((ext_vector_type(4)));

__device__ __forceinline__ unsigned short f2bf_rne(float f) {
    unsigned u = __float_as_uint(f);
    u += 0x7fffu + ((u >> 16) & 1u);
    return (unsigned short)(u >> 16);
}
__device__ __forceinline__ void split_pair(float a, float b, unsigned& hi, unsigned& lo) {
    unsigned ha = f2bf_rne(a), hb = f2bf_rne(b);
    hi = ha | (hb << 16);
    float ra = a - __uint_as_float(ha << 16);
    float rb = b - __uint_as_float(hb << 16);
    lo = (unsigned)f2bf_rne(ra) | ((unsigned)f2bf_rne(rb) << 16);
}

// value-semantics pack: two float4 -> bf16x8 hi + lo (no union, no memory obj)
#define SPLIT8(P, Q, HV, LV) do {                                         \
    unsigned h0_,h1_,h2_,h3_,l0_,l1_,l2_,l3_;                             \
    split_pair((P).x,(P).y,h0_,l0_); split_pair((P).z,(P).w,h1_,l1_);     \
    split_pair((Q).x,(Q).y,h2_,l2_); split_pair((Q).z,(Q).w,h3_,l3_);     \
    HV = __builtin_bit_cast(bf16x8,(u32x4){h0_,h1_,h2_,h3_});             \
    LV = __builtin_bit_cast(bf16x8,(u32x4){l0_,l1_,l2_,l3_});             \
} while(0)

// ---------------------------------------------------------------------------
// k_prep: W bf16 hi/lo split + wsqh[c] = -0.5*|W_c|^2 (MFMA C-operand init).
// ---------------------------------------------------------------------------
__global__ __launch_bounds__(256) void k_prep(const float* __restrict__ W,
                                              short* __restrict__ w_hi,
                                              short* __restrict__ w_lo,
                                              float* __restrict__ wsqh) {
    const int c = blockIdx.x * 256 + threadIdx.x;
    const float4* wr = (const float4*)(W + (c << 6));
    float a0 = 0.f, a1 = 0.f, a2 = 0.f, a3 = 0.f;
#pragma unroll
    for (int j = 0; j < 8; ++j) {
        float4 p = wr[2 * j], q = wr[2 * j + 1];
        a0 = fmaf(p.x, p.x, a0); a1 = fmaf(p.y, p.y, a1);
        a2 = fmaf(p.z, p.z, a2); a3 = fmaf(p.w, p.w, a3);
        a0 = fmaf(q.x, q.x, a0); a1 = fmaf(q.y, q.y, a1);
        a2 = fmaf(q.z, q.z, a2); a3 = fmaf(q.w, q.w, a3);
        bf16x8 hv, lv;
        SPLIT8(p, q, hv, lv);
        *(bf16x8*)(w_hi + (c << 6) + j * 8) = hv;
        *(bf16x8*)(w_lo + (c << 6) + j * 8) = lv;
    }
    wsqh[c] = -0.5f * ((a0 + a1) + (a2 + a3));
}

// ---------------------------------------------------------------------------
// Reference-arithmetic emulation (proven rounds 3-6): numpy fp32 pairwise
// sumsq + sgemm sequential-FMA dot.  Whole wave per row; broadcasts exact
// argmin index and D to ALL lanes.
// ---------------------------------------------------------------------------
__device__ __forceinline__ float f4c(const float4& v, int c) {
    return c == 0 ? v.x : c == 1 ? v.y : c == 2 ? v.z : v.w;
}

__device__ __forceinline__ float emu_sumsq(const float4 v[16]) {
    float s[16];
#pragma unroll
    for (int j = 0; j < 16; ++j) {
        float a = f4c(v[(j >> 2)     ], j & 3);
        float b = f4c(v[(j >> 2) + 4 ], j & 3);
        float c = f4c(v[(j >> 2) + 8 ], j & 3);
        float d = f4c(v[(j >> 2) + 12], j & 3);
        float pa = __fmul_rn(a, a), pb = __fmul_rn(b, b);
        float pc = __fmul_rn(c, c), pd = __fmul_rn(d, d);
        s[j] = __fadd_rn(__fadd_rn(pa, pb), __fadd_rn(pc, pd));
    }
    float u[8];
#pragma unroll
    for (int j = 0; j < 8; ++j) u[j] = __fadd_rn(s[j], s[j + 8]);
    float t[4];
#pragma unroll
    for (int j = 0; j < 4; ++j) t[j] = __fadd_rn(u[j], u[j + 4]);
    float w0 = __fadd_rn(t[0], t[2]);
    float w1 = __fadd_rn(t[1], t[3]);
    return __fadd_rn(w0, w1);
}

__device__ __forceinline__ void emu_row(int row, const float* __restrict__ z_e,
                                        const float* __restrict__ W, int lane,
                                        int& bc_out, float& bd_out) {
    float4 zz[16];
    const float4* zp = (const float4*)(z_e + ((size_t)row << 6));
#pragma unroll
    for (int j = 0; j < 16; ++j) zz[j] = zp[j];
    const float zsq = emu_sumsq(zz);

    float bestD = 1e30f;
    int   bestc = KCODES;
    for (int c0 = 0; c0 < KCODES; c0 += 64) {
        const int c = c0 + lane;
        const float4* wr = (const float4*)(W + (c << 6));
        float4 ww[16];
#pragma unroll
        for (int j = 0; j < 16; ++j) ww[j] = wr[j];
        const float wsqc = emu_sumsq(ww);
        float acc = 0.f;
#pragma unroll
        for (int j = 0; j < 16; ++j) {
            acc = __fmaf_rn(zz[j].x, ww[j].x, acc);
            acc = __fmaf_rn(zz[j].y, ww[j].y, acc);
            acc = __fmaf_rn(zz[j].z, ww[j].z, acc);
            acc = __fmaf_rn(zz[j].w, ww[j].w, acc);
        }
        const float twod = __fadd_rn(acc, acc);
        const float D = __fadd_rn(__fadd_rn(zsq, wsqc), -twod);
        if (D < bestD) { bestD = D; bestc = c; }
    }
#pragma unroll
    for (int off = 32; off > 0; off >>= 1) {
        float ov = __shfl_down(bestD, off);
        int   oc = __shfl_down(bestc, off);
        if (ov < bestD || (ov == bestD && oc < bestc)) { bestD = ov; bestc = oc; }
    }
    bc_out = __shfl(bestc, 0);
    bd_out = __shfl(bestD, 0);
}

// ---------------------------------------------------------------------------
// k_mega: 1 wave = 1 block = 64 rows, full-K scan.  No LDS, no barriers.
// All fragments individually NAMED (SROA-safe: no unions, no arrays) so they
// stay in VGPRs.  Screen: acc = dot - wsq/2 via C-init; argmin v <=> argmax
// acc; packed-int top-2 (idx in 10 low bits).  Then in-wave flag+rescue
// (ref-exact fp32 emulation), gather z_q_st = W[idx], loss partials.
// ---------------------------------------------------------------------------
__global__ __launch_bounds__(64, 2) void k_mega(const float* __restrict__ z_e,
                                                const short* __restrict__ w_hi,
                                                const short* __restrict__ w_lo,
                                                const float* __restrict__ wsqh,
                                                const float* __restrict__ W,
                                                float* __restrict__ out_zq,
                                                float* __restrict__ out_idx_f,
                                                float* __restrict__ partials) {
    const int lane = threadIdx.x;
    const int c4 = lane >> 4, r16 = lane & 15;
    const int rowbase = blockIdx.x << 6;

    // --- persistent z fragments (named) + per-row |z|^2 ---
    bf16x8 zh00, zh01, zh10, zh11, zh20, zh21, zh30, zh31;
    bf16x8 zl00, zl01, zl10, zl11, zl20, zl21, zl30, zl31;
    float zsq0, zsq1, zsq2, zsq3;

#define LOAD_Z(S, ZH0, ZH1, ZL0, ZL1, ZSQ) do {                           \
    const float* zr_ = z_e + (size_t)(rowbase + (S)*16 + r16) * 64 + c4*8;\
    float4 p0_ = *(const float4*)(zr_);                                   \
    float4 q0_ = *(const float4*)(zr_ + 4);                               \
    float4 p1_ = *(const float4*)(zr_ + 32);                              \
    float4 q1_ = *(const float4*)(zr_ + 36);                              \
    SPLIT8(p0_, q0_, ZH0, ZL0);                                           \
    SPLIT8(p1_, q1_, ZH1, ZL1);                                           \
    float a_ = 0.f;                                                       \
    a_ = fmaf(p0_.x,p0_.x,a_); a_ = fmaf(p0_.y,p0_.y,a_);                 \
    a_ = fmaf(p0_.z,p0_.z,a_); a_ = fmaf(p0_.w,p0_.w,a_);                 \
    a_ = fmaf(q0_.x,q0_.x,a_); a_ = fmaf(q0_.y,q0_.y,a_);                 \
    a_ = fmaf(q0_.z,q0_.z,a_); a_ = fmaf(q0_.w,q0_.w,a_);                 \
    a_ = fmaf(p1_.x,p1_.x,a_); a_ = fmaf(p1_.y,p1_.y,a_);                 \
    a_ = fmaf(p1_.z,p1_.z,a_); a_ = fmaf(p1_.w,p1_.w,a_);                 \
    a_ = fmaf(q1_.x,q1_.x,a_); a_ = fmaf(q1_.y,q1_.y,a_);                 \
    a_ = fmaf(q1_.z,q1_.z,a_); a_ = fmaf(q1_.w,q1_.w,a_);                 \
    a_ += __shfl_xor(a_, 16); a_ += __shfl_xor(a_, 32);                   \
    ZSQ = a_;                                                             \
} while(0)

    LOAD_Z(0, zh00, zh01, zl00, zl01, zsq0);
    LOAD_Z(1, zh10, zh11, zl10, zl11, zsq1);
    LOAD_Z(2, zh20, zh21, zl20, zl21, zsq2);
    LOAD_Z(3, zh30, zh31, zl30, zl31, zsq3);

    // --- screen: stream all 64 W code-tiles ---
    int b1_0 = (int)0x80000000, b1_1 = (int)0x80000000;
    int b1_2 = (int)0x80000000, b1_3 = (int)0x80000000;
    int b2_0 = (int)0x80000000, b2_1 = (int)0x80000000;
    int b2_2 = (int)0x80000000, b2_3 = (int)0x80000000;
    const int vlaneor = c4 << 2;
    const short* ph = w_hi + r16 * 64 + c4 * 8;
    const short* pl = w_lo + r16 * 64 + c4 * 8;

#define SCREEN_S(ZH0, ZH1, ZL0, ZL1, B1, B2) do {                                       \
    f32x4 acc_;                                                                         \
    acc_ = __builtin_amdgcn_mfma_f32_16x16x32_bf16(whf0, ZH0, wsqf, 0, 0, 0);           \
    acc_ = __builtin_amdgcn_mfma_f32_16x16x32_bf16(whf1, ZH1, acc_, 0, 0, 0);           \
    acc_ = __builtin_amdgcn_mfma_f32_16x16x32_bf16(whf0, ZL0, acc_, 0, 0, 0);           \
    acc_ = __builtin_amdgcn_mfma_f32_16x16x32_bf16(whf1, ZL1, acc_, 0, 0, 0);           \
    acc_ = __builtin_amdgcn_mfma_f32_16x16x32_bf16(wlf0, ZH0, acc_, 0, 0, 0);           \
    acc_ = __builtin_amdgcn_mfma_f32_16x16x32_bf16(wlf1, ZH1, acc_, 0, 0, 0);           \
    _Pragma("unroll")                                                                   \
    for (int r = 0; r < 4; ++r) {                                                       \
        int u_ = (__float_as_int(acc_[r]) & (int)0xFFFFFC00) | (orbase + r);            \
        B2 = max(B2, min(u_, B1));                                                      \
        B1 = max(B1, u_);                                                               \
    }                                                                                   \
} while(0)

#pragma unroll 2
    for (int t = 0; t < 64; ++t) {
        const int cbase = t << 4;
        bf16x8 whf0 = *(const bf16x8*)(ph);
        bf16x8 whf1 = *(const bf16x8*)(ph + 32);
        bf16x8 wlf0 = *(const bf16x8*)(pl);
        bf16x8 wlf1 = *(const bf16x8*)(pl + 32);
        ph += 1024; pl += 1024;
        const f32x4 wsqf = *(const f32x4*)(wsqh + cbase + c4 * 4);
        const int orbase = cbase | vlaneor;
        SCREEN_S(zh00, zh01, zl00, zl01, b1_0, b2_0);
        SCREEN_S(zh10, zh11, zl10, zl11, b1_1, b2_1);
        SCREEN_S(zh20, zh21, zl20, zl21, b1_2, b2_2);
        SCREEN_S(zh30, zh31, zl30, zl31, b1_3, b2_3);
    }

    // --- in-wave merge (lane-groups xor 16/32), flag near-ties ---
    int   idx0, idx1, idx2, idx3;
    float ls0, ls1, ls2, ls3;
    unsigned m0, m1, m2, m3;

#define MERGE_S(B1, B2, ZSQ, IDX, LOSS, MASK) do {                        \
    int x1_ = B1, x2_ = B2;                                               \
    _Pragma("unroll")                                                     \
    for (int m_ = 16; m_ <= 32; m_ <<= 1) {                               \
        int o1_ = __shfl_xor(x1_, m_);                                    \
        int o2_ = __shfl_xor(x2_, m_);                                    \
        x2_ = max(max(x2_, o2_), min(x1_, o1_));                          \
        x1_ = max(x1_, o1_);                                              \
    }                                                                     \
    float t1_ = __int_as_float(x1_ & (int)0xFFFFFC00);                    \
    float t2_ = __int_as_float(x2_ & (int)0xFFFFFC00);                    \
    IDX  = x1_ & 1023;                                                    \
    LOSS = fmaf(-2.f, t1_, ZSQ);                                          \
    bool flag_ = (t1_ - t2_) < fmaf(fabsf(t1_), 2.6e-4f, 1.6e-4f);        \
    MASK = (unsigned)(__ballot(flag_) & 0xFFFFull);                       \
} while(0)

    MERGE_S(b1_0, b2_0, zsq0, idx0, ls0, m0);
    MERGE_S(b1_1, b2_1, zsq1, idx1, ls1, m1);
    MERGE_S(b1_2, b2_2, zsq2, idx2, ls2, m2);
    MERGE_S(b1_3, b2_3, zsq3, idx3, ls3, m3);

    // --- in-wave ref-exact rescue of flagged rows ---
#define RESCUE_S(S, MASK, IDX, LOSS) do {                                 \
    unsigned m_ = MASK;                                                   \
    while (m_) {                                                          \
        int r_ = __ffs(m_) - 1; m_ &= m_ - 1;                             \
        int bc_; float bd_;                                               \
        emu_row(rowbase + (S)*16 + r_, z_e, W, lane, bc_, bd_);           \
        if (r16 == r_) { IDX = bc_; LOSS = bd_; }                         \
    }                                                                     \
} while(0)

    RESCUE_S(0, m0, idx0, ls0);
    RESCUE_S(1, m1, idx1, ls1);
    RESCUE_S(2, m2, idx2, ls2);
    RESCUE_S(3, m3, idx3, ls3);

    // --- outputs: indices ---
    if (lane < 16) {
        out_idx_f[rowbase +      lane] = (float)idx0;
        out_idx_f[rowbase + 16 + lane] = (float)idx1;
        out_idx_f[rowbase + 32 + lane] = (float)idx2;
        out_idx_f[rowbase + 48 + lane] = (float)idx3;
    }

    // --- gather z_q_st = W[idx] (exact; straight-through value == z_q) ---
#define GATHER_S(S, IDX) do {                                             \
    _Pragma("unroll")                                                     \
    for (int rr = 0; rr < 4; ++rr) {                                      \
        int src_ = rr * 4 + c4;                                           \
        int iv_  = __shfl(IDX, src_);                                     \
        float4 w4_ = *(const float4*)(W + (iv_ << 6) + (r16 << 2));       \
        *(float4*)(out_zq + (size_t)(rowbase + (S)*16 + rr*4 + c4) * 64   \
                   + (r16 << 2)) = w4_;                                   \
    }                                                                     \
} while(0)

    GATHER_S(0, idx0);
    GATHER_S(1, idx1);
    GATHER_S(2, idx2);
    GATHER_S(3, idx3);

    // --- loss partial (lanes 0..15 hold the 64 per-row losses once) ---
    float v = (lane < 16) ? (ls0 + ls1) + (ls2 + ls3) : 0.f;
#pragma unroll
    for (int off = 32; off > 0; off >>= 1) v += __shfl_down(v, off);
    if (lane == 0) partials[blockIdx.x] = v;
}

// ---------------------------------------------------------------------------
// k_loss: reduce 2048 block partials (both losses identical in forward).
// ---------------------------------------------------------------------------
__global__ __launch_bounds__(256) void k_loss(const float* __restrict__ partials,
                                              float* __restrict__ out) {
    float local = 0.f;
#pragma unroll
    for (int i = 0; i < 8; ++i) local += partials[threadIdx.x + i * 256];
#pragma unroll
    for (int off = 32; off > 0; off >>= 1) local += __shfl_down(local, off);
    __shared__ float s[4];
    if ((threadIdx.x & 63) == 0) s[threadIdx.x >> 6] = local;
    __syncthreads();
    if (threadIdx.x == 0) {
        float loss = ((s[0] + s[1]) + (s[2] + s[3])) * (1.f / 8388608.f);
        out[OUT_LOSS]     = loss;
        out[OUT_LOSS + 1] = loss;
    }
}

// ---------------------------------------------------------------------------
extern "C" void kernel_launch(void* const* d_in, const int* in_sizes, int n_in,
                              void* d_out, int out_size, void* d_ws, size_t ws_size,
                              hipStream_t stream) {
    const float* z_e = (const float*)d_in[0];
    const float* W   = (const float*)d_in[1];
    float* out       = (float*)d_out;

    short* w_hi     = (short*)d_ws;                     // 128 KB
    short* w_lo     = w_hi + KCODES * 64;               // 128 KB
    float* wsqh     = (float*)(w_lo + KCODES * 64);     // 4 KB
    float* partials = wsqh + KCODES;                    // 8 KB
    float* out_idx  = out + OUT_IDX;

    k_prep<<<4,    256, 0, stream>>>(W, w_hi, w_lo, wsqh);
    k_mega<<<2048, 64,  0, stream>>>(z_e, w_hi, w_lo, wsqh, W, out, out_idx, partials);
    k_loss<<<1,    256, 0, stream>>>(partials, out);
}